// Round 5
// baseline (132.168 us; speedup 1.0000x reference)
//
#include <hip/hip_runtime.h>

#define DEV __device__ __forceinline__

typedef __attribute__((ext_vector_type(8))) short bf16x8;
typedef __attribute__((ext_vector_type(4))) short bf16x4;
typedef __attribute__((ext_vector_type(4))) float f32x4;
typedef __attribute__((ext_vector_type(4))) unsigned int u32x4;

constexpr int Bb = 8;
constexpr int Nn = 1024;
constexpr int DIMm = 512;
constexpr int Hh = 8;
constexpr int Dh = 64;
constexpr int Mm = Bb * Nn;  // 8192
constexpr float LN10K = 9.210340371976184f;   // ln(10000)
constexpr float LOG2E = 1.4426950408889634f;  // log2(e)

DEV short f2bf(float f) {
  unsigned int u = __float_as_uint(f);
  u += 0x7fffu + ((u >> 16) & 1u);  // RNE
  return (short)(u >> 16);
}

DEV unsigned int cvtpk(float lo, float hi) {  // dword = {bf16(lo), bf16(hi)}
  unsigned int r;
  asm("v_cvt_pk_bf16_f32 %0, %1, %2" : "=v"(r) : "v"(lo), "v"(hi));
  return r;
}

DEV bf16x8 comb(bf16x4 lo, bf16x4 hi) {
  bf16x8 r;
  r[0] = lo[0]; r[1] = lo[1]; r[2] = lo[2]; r[3] = lo[3];
  r[4] = hi[0]; r[5] = hi[1]; r[6] = hi[2]; r[7] = hi[3];
  return r;
}

DEV f32x4 mfma16(bf16x8 a, bf16x8 b, f32x4 c) {
  return __builtin_amdgcn_mfma_f32_16x16x32_bf16(a, b, c, 0, 0, 0);
}

// ---------------------------------------------------------------------------
// prep: x -> bf16 ; w_qkv -> transposed bf16 [1536][512] ; w_out -> [512][512];
// RoPE cos/sin table [N][32] float2
// ---------------------------------------------------------------------------
__global__ void prep_kernel(const float* __restrict__ x, const float* __restrict__ wq,
                            const float* __restrict__ wo, short* __restrict__ x_bf,
                            short* __restrict__ wqkvT, short* __restrict__ woutT,
                            float2* __restrict__ tab) {
  int stride = gridDim.x * blockDim.x;
  int t = blockIdx.x * blockDim.x + threadIdx.x;
  for (int i = t; i < Mm * DIMm / 4; i += stride) {
    float4 v = ((const float4*)x)[i];
    bf16x4 o;
    o[0] = f2bf(v.x); o[1] = f2bf(v.y); o[2] = f2bf(v.z); o[3] = f2bf(v.w);
    *(bf16x4*)(x_bf + (size_t)i * 4) = o;
  }
  for (int i = t; i < 1536 * 512; i += stride) {
    int n = i >> 9, k = i & 511;
    wqkvT[i] = f2bf(wq[(size_t)k * 1536 + n]);
  }
  for (int i = t; i < 512 * 512; i += stride) {
    int n = i >> 9, k = i & 511;
    woutT[i] = f2bf(wo[(size_t)k * 512 + n]);
  }
  for (int i = t; i < Nn * 32; i += stride) {
    int n = i >> 5, d2 = i & 31;
    float fr = (float)n * __expf(-(float)(2 * d2) * (LN10K / 64.f));
    float sn, cs;
    __sincosf(fr, &sn, &cs);
    tab[i] = make_float2(cs, sn);
  }
}

// ---------------------------------------------------------------------------
// GEMM: A[Mx512] bf16 row-major, Bt[Ncols x 512] bf16 (pre-transposed).
// QKV==1: epilogue applies RoPE (table) + q-scale(0.125) and writes Q/K/V in
//   MFMA-fragment-order global layout (65536 shorts per bh):
//   Q,K (A/B-operand frag, row=n, k=d):
//     off = (n>>4)*1024 + (d>>5)*512 + ((n&15) + 16*((d&15)>>2))*8
//           + ((d&3) | ((d&16)>>2))
//   V (B-operand frag of PV, row=d, k=j):
//     off = (j>>6)*4096 + ((d>>4)*2 + ((j>>5)&1))*512
//           + ((d&15) + 16*((j&15)>>2))*8 + ((j&3) | ((j&16)>>2))
// QKV==0: plain f32 store.
// ---------------------------------------------------------------------------
template <int QKV>
__global__ __launch_bounds__(256) void gemm_k(const short* __restrict__ A,
                                              const short* __restrict__ Bt,
                                              float* __restrict__ outF,
                                              short* __restrict__ qr,
                                              short* __restrict__ kr,
                                              short* __restrict__ vt,
                                              const float2* __restrict__ tab) {
  __shared__ short Al[128][40];
  __shared__ short Bl[128][40];
  const int tid = threadIdx.x;
  const int lane = tid & 63;
  const int wid = tid >> 6;
  const int wm = wid >> 1, wn = wid & 1;
  const int li = lane & 15, g4 = (lane >> 4) << 2;
  const int m0 = blockIdx.x * 128, n0 = blockIdx.y * 128;

  f32x4 zero4 = {0.f, 0.f, 0.f, 0.f};
  f32x4 acc[4][4];
#pragma unroll
  for (int i = 0; i < 4; ++i)
#pragma unroll
    for (int j = 0; j < 4; ++j) acc[i][j] = zero4;

  for (int kt = 0; kt < 512; kt += 32) {
#pragma unroll
    for (int p = 0; p < 2; ++p) {
      int e = (tid + p * 256) * 8;
      int r = e >> 5, c = e & 31;
      *(u32x4*)(&Al[r][c]) = *(const u32x4*)(A + (size_t)(m0 + r) * 512 + kt + c);
      *(u32x4*)(&Bl[r][c]) = *(const u32x4*)(Bt + (size_t)(n0 + r) * 512 + kt + c);
    }
    __syncthreads();
    bf16x8 af[4], bfr[4];
#pragma unroll
    for (int mt = 0; mt < 4; ++mt) {
      int row = wm * 64 + mt * 16 + li;
      af[mt] = comb(*(const bf16x4*)(&Al[row][g4]), *(const bf16x4*)(&Al[row][16 + g4]));
    }
#pragma unroll
    for (int nt = 0; nt < 4; ++nt) {
      int row = wn * 64 + nt * 16 + li;
      bfr[nt] = comb(*(const bf16x4*)(&Bl[row][g4]), *(const bf16x4*)(&Bl[row][16 + g4]));
    }
#pragma unroll
    for (int mt = 0; mt < 4; ++mt)
#pragma unroll
      for (int nt = 0; nt < 4; ++nt)
        acc[mt][nt] = mfma16(af[mt], bfr[nt], acc[mt][nt]);
    __syncthreads();
  }

  if (QKV == 0) {
#pragma unroll
    for (int mt = 0; mt < 4; ++mt) {
      int mb = m0 + wm * 64 + mt * 16 + g4;
#pragma unroll
      for (int nt = 0; nt < 4; ++nt) {
        int c = n0 + wn * 64 + nt * 16 + li;
#pragma unroll
        for (int r = 0; r < 4; ++r) outF[(size_t)(mb + r) * 512 + c] = acc[mt][nt][r];
      }
    }
  } else {
    const int sec = n0 >> 9;  // 0=q 1=k 2=v
#pragma unroll
    for (int mt = 0; mt < 4; ++mt) {
      int mb = m0 + wm * 64 + mt * 16 + g4;
      int b_ = mb >> 10;
      int nb = mb & 1023;  // token index; nb ≡ g4 (mod 16)
#pragma unroll
      for (int nt = 0; nt < 4; ++nt) {
        int c = n0 + wn * 64 + nt * 16 + li;
        int cs = c & 511;
        int hh = cs >> 6, d = cs & 63;
        size_t bhoff = (size_t)(b_ * Hh + hh) * 65536;
        if (sec == 2) {
          int dt = d >> 4, liD = d & 15;
          int kkJ = (nb >> 5) & 1;
          int gj = (nb & 15) >> 2;
          int s0 = (nb & 16) >> 2;  // 0 or 4
          size_t off = bhoff + (size_t)(nb >> 6) * 4096 +
                       (size_t)((dt * 2 + kkJ) * 512) + (size_t)(liD + 16 * gj) * 8 + s0;
          uint2 st;
          st.x = cvtpk(acc[mt][nt][0], acc[mt][nt][1]);
          st.y = cvtpk(acc[mt][nt][2], acc[mt][nt][3]);
          *(uint2*)(vt + off) = st;
        } else {
          int kkD = d >> 5;
          int gd = (d & 15) >> 2;
          int sD = (d & 3) | ((d & 16) >> 2);
          size_t off = bhoff + (size_t)(nb >> 4) * 1024 + (size_t)(kkD * 512) +
                       (size_t)((nb & 15) + 16 * gd) * 8 + sD;
          short* dst = (sec == 0 ? qr : kr) + off;
#pragma unroll
          for (int r = 0; r < 4; ++r) {
            float v0 = acc[mt][nt][r];
            float vp = __shfl_xor(v0, 1, 64);  // RoPE pair partner (adjacent d)
            float2 cssn = tab[(size_t)(nb + r) * 32 + (d >> 1)];
            float rot = (d & 1) ? vp : -vp;
            float res = v0 * cssn.x + rot * cssn.y;
            if (sec == 0) res *= 0.125f;  // Dh^-0.5 (e-domain; LOG2E applied in exp)
            dst[(size_t)r * 8] = f2bf(res);
          }
        }
      }
    }
  }
}

// ---------------------------------------------------------------------------
// Flash attention: direct-from-global fragment reads, explicit 2-deep K/bias
// register pipeline (named tA/tB, manual 2x unroll) + sched_barrier load
// pinning. KVBLK=32: 4 K-frag + 4 V-frag b128 + 2 bias b128 loads, 8 MFMA.
// Block mapping: h = bid&7 (XCD pin), b_ = (bid>>3)&7 (FAST), it = bid>>6
// (SLOW) -> CU-resident blocks share (b,h): identical K/V stream, L1-served.
// ---------------------------------------------------------------------------
struct KT {
  bf16x8 k0, k1, k2, k3;  // (js0,kk0) (js0,kk1) (js1,kk0) (js1,kk1)
  f32x4 b0, b1;           // bias C-init for js0, js1
};

DEV void loadK(KT& T, const short* kb, const float* br, int t) {
  const short* p = kb + (size_t)t * 2048;
  T.k0 = *(const bf16x8*)(p);
  T.k1 = *(const bf16x8*)(p + 512);
  T.k2 = *(const bf16x8*)(p + 1024);
  T.k3 = *(const bf16x8*)(p + 1536);
  T.b0 = *(const f32x4*)(br + t * 32);
  T.b1 = *(const f32x4*)(br + t * 32 + 16);
}

DEV void loadV(bf16x8* v, const short* vb, int t) {
  const short* p = vb + (size_t)(t >> 1) * 4096 + (size_t)(t & 1) * 512;
  v[0] = *(const bf16x8*)(p);
  v[1] = *(const bf16x8*)(p + 1024);
  v[2] = *(const bf16x8*)(p + 2048);
  v[3] = *(const bf16x8*)(p + 3072);
}

DEV void tileC(const KT& T, const bf16x8* v, bf16x8 qf0, bf16x8 qf1,
               f32x4* acc, float& m_run, float& l_run, int g4) {
  __builtin_amdgcn_s_setprio(1);
  f32x4 s0 = mfma16(T.k0, qf0, T.b0);
  f32x4 s1 = mfma16(T.k2, qf0, T.b1);
  s0 = mfma16(T.k1, qf1, s0);
  s1 = mfma16(T.k3, qf1, s1);
  __builtin_amdgcn_s_setprio(0);

  float mx = fmaxf(fmaxf(fmaxf(s0[0], s0[1]), fmaxf(s0[2], s0[3])),
                   fmaxf(fmaxf(s1[0], s1[1]), fmaxf(s1[2], s1[3])));
  mx = fmaxf(mx, __shfl_xor(mx, 16, 64));
  mx = fmaxf(mx, __shfl_xor(mx, 32, 64));

  if (!__all(mx - m_run <= 8.0f)) {  // defer-max (T13)
    float mn = fmaxf(m_run, mx);
    float sc = __builtin_amdgcn_exp2f((m_run - mn) * LOG2E);
    l_run *= sc;
    m_run = mn;
    float fs0 = __shfl(sc, g4 + 0, 64), fs1 = __shfl(sc, g4 + 1, 64);
    float fs2 = __shfl(sc, g4 + 2, 64), fs3 = __shfl(sc, g4 + 3, 64);
#pragma unroll
    for (int dt = 0; dt < 4; ++dt) {
      acc[dt][0] *= fs0; acc[dt][1] *= fs1;
      acc[dt][2] *= fs2; acc[dt][3] *= fs3;
    }
  }

  float nm = -m_run * LOG2E;
  float rs = 0.f;
  float e0[4], e1[4];
#pragma unroll
  for (int r = 0; r < 4; ++r) {
    e0[r] = __builtin_amdgcn_exp2f(__builtin_fmaf(s0[r], LOG2E, nm));
    e1[r] = __builtin_amdgcn_exp2f(__builtin_fmaf(s1[r], LOG2E, nm));
    rs += e0[r] + e1[r];
  }
  rs += __shfl_xor(rs, 16, 64);
  rs += __shfl_xor(rs, 32, 64);
  l_run += rs;

  union { bf16x8 v8; unsigned int d[4]; } u;
  u.d[0] = cvtpk(e0[0], e0[1]);
  u.d[1] = cvtpk(e0[2], e0[3]);
  u.d[2] = cvtpk(e1[0], e1[1]);
  u.d[3] = cvtpk(e1[2], e1[3]);

  __builtin_amdgcn_s_setprio(1);
#pragma unroll
  for (int dt = 0; dt < 4; ++dt) acc[dt] = mfma16(u.v8, v[dt], acc[dt]);
  __builtin_amdgcn_s_setprio(0);
}

__global__ __launch_bounds__(256, 4) void attn_k(const short* __restrict__ qf_g,
                                                 const short* __restrict__ kf_g,
                                                 const short* __restrict__ vf_g,
                                                 const float* __restrict__ bias,
                                                 short* __restrict__ ao) {
  const int tid = threadIdx.x, lane = tid & 63, w = tid >> 6;
  const int li = lane & 15, g4 = (lane >> 4) << 2;
  // Block mapping (see header): h pin to XCD, b_ fast, it slow.
  const int bid = blockIdx.x;
  const int h = bid & 7;
  const int b_ = (bid >> 3) & 7;
  const int it = bid >> 6;
  const int bh = b_ * 8 + h;
  const int i0 = it * 64;
  const int iq = i0 + w * 16 + li;  // this lane's q row

  const short* qbase = qf_g + (size_t)bh * 65536 + (size_t)(it * 4 + w) * 1024 + lane * 8;
  bf16x8 qf0 = *(const bf16x8*)(qbase);
  bf16x8 qf1 = *(const bf16x8*)(qbase + 512);

  const short* kb = kf_g + (size_t)bh * 65536 + (size_t)lane * 8;
  const short* vb = vf_g + (size_t)bh * 65536 + (size_t)lane * 8;
  const float* br = bias + ((size_t)h * Nn + iq) * Nn + g4;

  float m_run = -1e30f, l_run = 0.f;
  f32x4 zero4 = {0.f, 0.f, 0.f, 0.f};
  f32x4 acc[4];
#pragma unroll
  for (int i = 0; i < 4; ++i) acc[i] = zero4;

  KT tA, tB;
  bf16x8 vr[4];
  loadK(tA, kb, br, 0);

#pragma unroll 1
  for (int t = 0; t < 32; t += 2) {
    loadK(tB, kb, br, t + 1);   // prefetch next K+bias
    loadV(vr, vb, t);           // V for current tile (consumed post-softmax)
    __builtin_amdgcn_sched_barrier(0x38F);  // pin VMEM above compute
    tileC(tA, vr, qf0, qf1, acc, m_run, l_run, g4);

    if (t + 2 < 32) loadK(tA, kb, br, t + 2);
    loadV(vr, vb, t + 1);
    __builtin_amdgcn_sched_barrier(0x38F);
    tileC(tB, vr, qf0, qf1, acc, m_run, l_run, g4);
  }

  float rl = 1.f / l_run;
  float fr0 = __shfl(rl, g4 + 0, 64), fr1 = __shfl(rl, g4 + 1, 64);
  float fr2 = __shfl(rl, g4 + 2, 64), fr3 = __shfl(rl, g4 + 3, 64);
#pragma unroll
  for (int dt = 0; dt < 4; ++dt) {
    float fr[4] = {fr0, fr1, fr2, fr3};
#pragma unroll
    for (int r = 0; r < 4; ++r) {
      int i_ = i0 + w * 16 + g4 + r;
      ao[((size_t)(b_ * Nn + i_)) * 512 + h * 64 + dt * 16 + li] =
          f2bf(acc[dt][r] * fr[r]);
    }
  }
}

// ---------------------------------------------------------------------------
extern "C" void kernel_launch(void* const* d_in, const int* in_sizes, int n_in,
                              void* d_out, int out_size, void* d_ws, size_t ws_size,
                              hipStream_t stream) {
  const float* x = (const float*)d_in[0];
  const float* pb = (const float*)d_in[1];
  const float* wq = (const float*)d_in[2];
  const float* wo = (const float*)d_in[3];
  float* out = (float*)d_out;

  short* w = (short*)d_ws;
  short* x_bf = w;  w += (size_t)Mm * DIMm;      // 8 MB
  short* wqkvT = w; w += 1536 * 512;             // 1.5 MB
  short* woutT = w; w += 512 * 512;              // 0.5 MB
  short* qr = w;    w += (size_t)Mm * DIMm;      // 8 MB (frag-order)
  short* kr = w;    w += (size_t)Mm * DIMm;      // 8 MB (frag-order)
  short* vt = w;    w += (size_t)Mm * DIMm;      // 8 MB (frag-order)
  float2* tab = (float2*)w; w += Nn * 32 * 4;    // 256 KB
  short* ao = x_bf;  // x_bf dead after qkv GEMM

  prep_kernel<<<1024, 256, 0, stream>>>(x, wq, wo, x_bf, wqkvT, woutT, tab);
  gemm_k<1><<<dim3(64, 12), 256, 0, stream>>>(x_bf, wqkvT, nullptr, qr, kr, vt, tab);
  attn_k<<<1024, 256, 0, stream>>>(qr, kr, vt, pb, ao);
  gemm_k<0><<<dim3(64, 4), 256, 0, stream>>>(ao, woutT, out, nullptr, nullptr, nullptr, tab);
}

// Round 6
// 117.640 us; speedup vs baseline: 1.1235x; 1.1235x over previous
//
#include <hip/hip_runtime.h>

#define DEV __device__ __forceinline__

typedef __attribute__((ext_vector_type(8))) short bf16x8;
typedef __attribute__((ext_vector_type(4))) short bf16x4;
typedef __attribute__((ext_vector_type(4))) float f32x4;
typedef __attribute__((ext_vector_type(4))) unsigned int u32x4;

constexpr int Bb = 8;
constexpr int Nn = 1024;
constexpr int DIMm = 512;
constexpr int Hh = 8;
constexpr int Dh = 64;
constexpr int Mm = Bb * Nn;  // 8192
constexpr float LN10K = 9.210340371976184f;   // ln(10000)
constexpr float LOG2E = 1.4426950408889634f;  // log2(e)

DEV short f2bf(float f) {
  unsigned int u = __float_as_uint(f);
  u += 0x7fffu + ((u >> 16) & 1u);  // RNE
  return (short)(u >> 16);
}

DEV unsigned int cvtpk(float lo, float hi) {  // dword = {bf16(lo), bf16(hi)}
  unsigned int r;
  asm("v_cvt_pk_bf16_f32 %0, %1, %2" : "=v"(r) : "v"(lo), "v"(hi));
  return r;
}

DEV bf16x8 comb(bf16x4 lo, bf16x4 hi) {
  bf16x8 r;
  r[0] = lo[0]; r[1] = lo[1]; r[2] = lo[2]; r[3] = lo[3];
  r[4] = hi[0]; r[5] = hi[1]; r[6] = hi[2]; r[7] = hi[3];
  return r;
}

DEV f32x4 mfma16(bf16x8 a, bf16x8 b, f32x4 c) {
  return __builtin_amdgcn_mfma_f32_16x16x32_bf16(a, b, c, 0, 0, 0);
}

DEV void gload16(const void* g, void* l) {
  __builtin_amdgcn_global_load_lds(
      (const __attribute__((address_space(1))) void*)g,
      (__attribute__((address_space(3))) void*)l, 16, 0, 0);
}

// ---------------------------------------------------------------------------
// prep: x -> bf16 ; w_qkv -> transposed bf16 [1536][512] ; w_out -> [512][512];
// RoPE cos/sin table [N][32] float2
// ---------------------------------------------------------------------------
__global__ void prep_kernel(const float* __restrict__ x, const float* __restrict__ wq,
                            const float* __restrict__ wo, short* __restrict__ x_bf,
                            short* __restrict__ wqkvT, short* __restrict__ woutT,
                            float2* __restrict__ tab) {
  int stride = gridDim.x * blockDim.x;
  int t = blockIdx.x * blockDim.x + threadIdx.x;
  for (int i = t; i < Mm * DIMm / 4; i += stride) {
    float4 v = ((const float4*)x)[i];
    bf16x4 o;
    o[0] = f2bf(v.x); o[1] = f2bf(v.y); o[2] = f2bf(v.z); o[3] = f2bf(v.w);
    *(bf16x4*)(x_bf + (size_t)i * 4) = o;
  }
  for (int i = t; i < 1536 * 512; i += stride) {
    int n = i >> 9, k = i & 511;
    wqkvT[i] = f2bf(wq[(size_t)k * 1536 + n]);
  }
  for (int i = t; i < 512 * 512; i += stride) {
    int n = i >> 9, k = i & 511;
    woutT[i] = f2bf(wo[(size_t)k * 512 + n]);
  }
  for (int i = t; i < Nn * 32; i += stride) {
    int n = i >> 5, d2 = i & 31;
    float fr = (float)n * __expf(-(float)(2 * d2) * (LN10K / 64.f));
    float sn, cs;
    __sincosf(fr, &sn, &cs);
    tab[i] = make_float2(cs, sn);
  }
}

// ---------------------------------------------------------------------------
// GEMM: A[Mx512] bf16 row-major, Bt[Ncols x 512] bf16 (pre-transposed).
// QKV==1: epilogue applies RoPE (table) + q-scale(0.125) and writes Q/K/V in
//   MFMA-fragment-order global layout (65536 shorts per bh):
//   Q,K (A/B-operand frag, row=n, k=d):
//     off = (n>>4)*1024 + (d>>5)*512 + ((n&15) + 16*((d&15)>>2))*8
//           + ((d&3) | ((d&16)>>2))
//   V (B-operand frag of PV, row=d, k=j):
//     off = (j>>6)*4096 + ((d>>4)*2 + ((j>>5)&1))*512
//           + ((d&15) + 16*((j&15)>>2))*8 + ((j&3) | ((j&16)>>2))
// QKV==0: plain f32 store.
// ---------------------------------------------------------------------------
template <int QKV>
__global__ __launch_bounds__(256) void gemm_k(const short* __restrict__ A,
                                              const short* __restrict__ Bt,
                                              float* __restrict__ outF,
                                              short* __restrict__ qr,
                                              short* __restrict__ kr,
                                              short* __restrict__ vt,
                                              const float2* __restrict__ tab) {
  __shared__ short Al[128][40];
  __shared__ short Bl[128][40];
  const int tid = threadIdx.x;
  const int lane = tid & 63;
  const int wid = tid >> 6;
  const int wm = wid >> 1, wn = wid & 1;
  const int li = lane & 15, g4 = (lane >> 4) << 2;
  const int m0 = blockIdx.x * 128, n0 = blockIdx.y * 128;

  f32x4 zero4 = {0.f, 0.f, 0.f, 0.f};
  f32x4 acc[4][4];
#pragma unroll
  for (int i = 0; i < 4; ++i)
#pragma unroll
    for (int j = 0; j < 4; ++j) acc[i][j] = zero4;

  for (int kt = 0; kt < 512; kt += 32) {
#pragma unroll
    for (int p = 0; p < 2; ++p) {
      int e = (tid + p * 256) * 8;
      int r = e >> 5, c = e & 31;
      *(u32x4*)(&Al[r][c]) = *(const u32x4*)(A + (size_t)(m0 + r) * 512 + kt + c);
      *(u32x4*)(&Bl[r][c]) = *(const u32x4*)(Bt + (size_t)(n0 + r) * 512 + kt + c);
    }
    __syncthreads();
    bf16x8 af[4], bfr[4];
#pragma unroll
    for (int mt = 0; mt < 4; ++mt) {
      int row = wm * 64 + mt * 16 + li;
      af[mt] = comb(*(const bf16x4*)(&Al[row][g4]), *(const bf16x4*)(&Al[row][16 + g4]));
    }
#pragma unroll
    for (int nt = 0; nt < 4; ++nt) {
      int row = wn * 64 + nt * 16 + li;
      bfr[nt] = comb(*(const bf16x4*)(&Bl[row][g4]), *(const bf16x4*)(&Bl[row][16 + g4]));
    }
#pragma unroll
    for (int mt = 0; mt < 4; ++mt)
#pragma unroll
      for (int nt = 0; nt < 4; ++nt)
        acc[mt][nt] = mfma16(af[mt], bfr[nt], acc[mt][nt]);
    __syncthreads();
  }

  if (QKV == 0) {
#pragma unroll
    for (int mt = 0; mt < 4; ++mt) {
      int mb = m0 + wm * 64 + mt * 16 + g4;
#pragma unroll
      for (int nt = 0; nt < 4; ++nt) {
        int c = n0 + wn * 64 + nt * 16 + li;
#pragma unroll
        for (int r = 0; r < 4; ++r) outF[(size_t)(mb + r) * 512 + c] = acc[mt][nt][r];
      }
    }
  } else {
    const int sec = n0 >> 9;  // 0=q 1=k 2=v
#pragma unroll
    for (int mt = 0; mt < 4; ++mt) {
      int mb = m0 + wm * 64 + mt * 16 + g4;
      int b_ = mb >> 10;
      int nb = mb & 1023;  // token index; nb ≡ g4 (mod 16)
#pragma unroll
      for (int nt = 0; nt < 4; ++nt) {
        int c = n0 + wn * 64 + nt * 16 + li;
        int cs = c & 511;
        int hh = cs >> 6, d = cs & 63;
        size_t bhoff = (size_t)(b_ * Hh + hh) * 65536;
        if (sec == 2) {
          int dt = d >> 4, liD = d & 15;
          int kkJ = (nb >> 5) & 1;
          int gj = (nb & 15) >> 2;
          int s0 = (nb & 16) >> 2;  // 0 or 4
          size_t off = bhoff + (size_t)(nb >> 6) * 4096 +
                       (size_t)((dt * 2 + kkJ) * 512) + (size_t)(liD + 16 * gj) * 8 + s0;
          uint2 st;
          st.x = cvtpk(acc[mt][nt][0], acc[mt][nt][1]);
          st.y = cvtpk(acc[mt][nt][2], acc[mt][nt][3]);
          *(uint2*)(vt + off) = st;
        } else {
          int kkD = d >> 5;
          int gd = (d & 15) >> 2;
          int sD = (d & 3) | ((d & 16) >> 2);
          size_t off = bhoff + (size_t)(nb >> 4) * 1024 + (size_t)(kkD * 512) +
                       (size_t)((nb & 15) + 16 * gd) * 8 + sD;
          short* dst = (sec == 0 ? qr : kr) + off;
#pragma unroll
          for (int r = 0; r < 4; ++r) {
            float v0 = acc[mt][nt][r];
            float vp = __shfl_xor(v0, 1, 64);  // RoPE pair partner (adjacent d)
            float2 cssn = tab[(size_t)(nb + r) * 32 + (d >> 1)];
            float rot = (d & 1) ? vp : -vp;
            float res = v0 * cssn.x + rot * cssn.y;
            if (sec == 0) res *= 0.125f;  // Dh^-0.5 (e-domain; LOG2E applied in exp)
            dst[(size_t)r * 8] = f2bf(res);
          }
        }
      }
    }
  }
}

// ---------------------------------------------------------------------------
// Flash attention v6: T3 2-phase double-buffered LDS pipeline.
// Per tile (KVBLK=64): STAGE(next tile via global_load_lds, zero-VGPR in
// flight) -> compute current (ds_read_b128 frags + 16 MFMA + in-reg softmax)
// -> vmcnt(0) + s_barrier (loads had full compute to land). K/V live in
// frag-order global layout; LDS image is linear so every fragment read is
// ds_read_b128 at base + lane*16 (conflict-free). All 4 waves broadcast-read
// the same K/V. Bias prefetched 1 tile deep into registers (bbA/bbB).
// ---------------------------------------------------------------------------
constexpr int KVB = 64;
constexpr int NTT = Nn / KVB;  // 16

__global__ __launch_bounds__(256, 4) void attn_k(const short* __restrict__ qf_g,
                                                 const short* __restrict__ kf_g,
                                                 const short* __restrict__ vf_g,
                                                 const float* __restrict__ bias,
                                                 short* __restrict__ ao) {
  __shared__ short Kls[2][4096];  // [buf][64j x 64d frag-order], 8 KB each
  __shared__ short Vls[2][4096];  // [buf][64d x 64j frag-order], 8 KB each
  const int tid = threadIdx.x, lane = tid & 63, w = tid >> 6;
  const int li = lane & 15, g4 = (lane >> 4) << 2;
  // Block mapping: h pin to XCD, b_ fast, it slow.
  const int bid = blockIdx.x;
  const int h = bid & 7;
  const int b_ = (bid >> 3) & 7;
  const int it = bid >> 6;
  const int bh = b_ * 8 + h;
  const int i0 = it * 64;
  const int iq = i0 + w * 16 + li;  // this lane's q row

  const short* qbase = qf_g + (size_t)bh * 65536 + (size_t)(it * 4 + w) * 1024 + lane * 8;
  bf16x8 qf0 = *(const bf16x8*)(qbase);
  bf16x8 qf1 = *(const bf16x8*)(qbase + 512);

  const short* kb = kf_g + (size_t)bh * 65536;
  const short* vb = vf_g + (size_t)bh * 65536;
  const float* br = bias + ((size_t)h * Nn + iq) * Nn + g4;

  float m_run = -1e30f, l_run = 0.f;
  f32x4 zero4 = {0.f, 0.f, 0.f, 0.f};
  f32x4 acc[4];
#pragma unroll
  for (int i = 0; i < 4; ++i) acc[i] = zero4;

  // ---- staging macro: 4 x gload16 per thread (K 8KB + V 8KB per tile) ----
#define STAGE_TILE(T, BUF)                                                  \
  do {                                                                      \
    const short* ks_ = kb + (size_t)(T) * 4096;                             \
    const short* vs_ = vb + (size_t)(T) * 4096;                             \
    gload16(ks_ + (size_t)tid * 8, &Kls[BUF][(size_t)(w * 64) * 8]);        \
    gload16(ks_ + (size_t)(256 + tid) * 8,                                  \
            &Kls[BUF][(size_t)(256 + w * 64) * 8]);                         \
    gload16(vs_ + (size_t)tid * 8, &Vls[BUF][(size_t)(w * 64) * 8]);        \
    gload16(vs_ + (size_t)(256 + tid) * 8,                                  \
            &Vls[BUF][(size_t)(256 + w * 64) * 8]);                         \
  } while (0)

  f32x4 bbA[4], bbB[4];

  // prologue: stage tile 0, load its bias
  STAGE_TILE(0, 0);
#pragma unroll
  for (int js = 0; js < 4; ++js) bbA[js] = *(const f32x4*)(br + js * 16);
  asm volatile("s_waitcnt vmcnt(0)" ::: "memory");
  __builtin_amdgcn_s_barrier();

  int cur = 0;
#pragma unroll 1
  for (int t = 0; t < NTT; ++t) {
    // phase 1: issue next tile's staging (stays in flight across compute)
    if (t + 1 < NTT) {
      STAGE_TILE(t + 1, cur ^ 1);
#pragma unroll
      for (int js = 0; js < 4; ++js)
        bbB[js] = *(const f32x4*)(br + (t + 1) * 64 + js * 16);
    }

    // phase 2: compute current tile from LDS
    const short* KB = &Kls[cur][0];
    const short* VB = &Vls[cur][0];
    f32x4 s[4];
    __builtin_amdgcn_s_setprio(1);
#pragma unroll
    for (int js = 0; js < 4; ++js) {
      bf16x8 k0 = *(const bf16x8*)(KB + js * 1024 + lane * 8);
      bf16x8 k1 = *(const bf16x8*)(KB + js * 1024 + 512 + lane * 8);
      f32x4 sa = mfma16(k0, qf0, bbA[js]);
      s[js] = mfma16(k1, qf1, sa);
    }
    __builtin_amdgcn_s_setprio(0);

    // row max
    float mx = fmaxf(fmaxf(fmaxf(s[0][0], s[0][1]), fmaxf(s[0][2], s[0][3])),
                     fmaxf(fmaxf(s[1][0], s[1][1]), fmaxf(s[1][2], s[1][3])));
    float mx2 = fmaxf(fmaxf(fmaxf(s[2][0], s[2][1]), fmaxf(s[2][2], s[2][3])),
                      fmaxf(fmaxf(s[3][0], s[3][1]), fmaxf(s[3][2], s[3][3])));
    mx = fmaxf(mx, mx2);
    mx = fmaxf(mx, __shfl_xor(mx, 16, 64));
    mx = fmaxf(mx, __shfl_xor(mx, 32, 64));

    if (!__all(mx - m_run <= 8.0f)) {  // defer-max (T13)
      float mn = fmaxf(m_run, mx);
      float sc = __builtin_amdgcn_exp2f((m_run - mn) * LOG2E);
      l_run *= sc;
      m_run = mn;
      float fs0 = __shfl(sc, g4 + 0, 64), fs1 = __shfl(sc, g4 + 1, 64);
      float fs2 = __shfl(sc, g4 + 2, 64), fs3 = __shfl(sc, g4 + 3, 64);
#pragma unroll
      for (int dt = 0; dt < 4; ++dt) {
        acc[dt][0] *= fs0; acc[dt][1] *= fs1;
        acc[dt][2] *= fs2; acc[dt][3] *= fs3;
      }
    }

    float nm = -m_run * LOG2E;
    float rs = 0.f;
#pragma unroll
    for (int js = 0; js < 4; ++js)
#pragma unroll
      for (int r = 0; r < 4; ++r) {
        float p = __builtin_amdgcn_exp2f(__builtin_fmaf(s[js][r], LOG2E, nm));
        s[js][r] = p;
        rs += p;
      }
    rs += __shfl_xor(rs, 16, 64);
    rs += __shfl_xor(rs, 32, 64);
    l_run += rs;

    // P -> bf16 A-frags: pf[kk] covers j in [32kk, 32kk+32)
    bf16x8 pf[2];
#pragma unroll
    for (int kk = 0; kk < 2; ++kk) {
      union { bf16x8 v8; unsigned int d[4]; } u;
      u.d[0] = cvtpk(s[2 * kk][0], s[2 * kk][1]);
      u.d[1] = cvtpk(s[2 * kk][2], s[2 * kk][3]);
      u.d[2] = cvtpk(s[2 * kk + 1][0], s[2 * kk + 1][1]);
      u.d[3] = cvtpk(s[2 * kk + 1][2], s[2 * kk + 1][3]);
      pf[kk] = u.v8;
    }

    // PV
    __builtin_amdgcn_s_setprio(1);
#pragma unroll
    for (int dt = 0; dt < 4; ++dt) {
      bf16x8 vf0 = *(const bf16x8*)(VB + (dt * 2 + 0) * 512 + lane * 8);
      bf16x8 vf1 = *(const bf16x8*)(VB + (dt * 2 + 1) * 512 + lane * 8);
      f32x4 a = mfma16(pf[0], vf0, acc[dt]);
      acc[dt] = mfma16(pf[1], vf1, a);
    }
    __builtin_amdgcn_s_setprio(0);

    // phase 3: next tile's staging is done by now; sync buffers
    asm volatile("s_waitcnt vmcnt(0)" ::: "memory");
    __builtin_amdgcn_s_barrier();
#pragma unroll
    for (int js = 0; js < 4; ++js) bbA[js] = bbB[js];
    cur ^= 1;
  }
#undef STAGE_TILE

  float rl = 1.f / l_run;
  float fr0 = __shfl(rl, g4 + 0, 64), fr1 = __shfl(rl, g4 + 1, 64);
  float fr2 = __shfl(rl, g4 + 2, 64), fr3 = __shfl(rl, g4 + 3, 64);
#pragma unroll
  for (int dt = 0; dt < 4; ++dt) {
    float fr[4] = {fr0, fr1, fr2, fr3};
#pragma unroll
    for (int r = 0; r < 4; ++r) {
      int i_ = i0 + w * 16 + g4 + r;
      ao[((size_t)(b_ * Nn + i_)) * 512 + h * 64 + dt * 16 + li] =
          f2bf(acc[dt][r] * fr[r]);
    }
  }
}

// ---------------------------------------------------------------------------
extern "C" void kernel_launch(void* const* d_in, const int* in_sizes, int n_in,
                              void* d_out, int out_size, void* d_ws, size_t ws_size,
                              hipStream_t stream) {
  const float* x = (const float*)d_in[0];
  const float* pb = (const float*)d_in[1];
  const float* wq = (const float*)d_in[2];
  const float* wo = (const float*)d_in[3];
  float* out = (float*)d_out;

  short* w = (short*)d_ws;
  short* x_bf = w;  w += (size_t)Mm * DIMm;      // 8 MB
  short* wqkvT = w; w += 1536 * 512;             // 1.5 MB
  short* woutT = w; w += 512 * 512;              // 0.5 MB
  short* qr = w;    w += (size_t)Mm * DIMm;      // 8 MB (frag-order)
  short* kr = w;    w += (size_t)Mm * DIMm;      // 8 MB (frag-order)
  short* vt = w;    w += (size_t)Mm * DIMm;      // 8 MB (frag-order)
  float2* tab = (float2*)w; w += Nn * 32 * 4;    // 256 KB
  short* ao = x_bf;  // x_bf dead after qkv GEMM

  prep_kernel<<<1024, 256, 0, stream>>>(x, wq, wo, x_bf, wqkvT, woutT, tab);
  gemm_k<1><<<dim3(64, 12), 256, 0, stream>>>(x_bf, wqkvT, nullptr, qr, kr, vt, tab);
  attn_k<<<1024, 256, 0, stream>>>(qr, kr, vt, pb, ao);
  gemm_k<0><<<dim3(64, 4), 256, 0, stream>>>(ao, woutT, out, nullptr, nullptr, nullptr, tab);
}